// Round 8
// baseline (418.121 us; speedup 1.0000x reference)
//
#include <hip/hip_runtime.h>
#include <hip/hip_cooperative_groups.h>

namespace cg = cooperative_groups;

// T=4096, B=8, E=512. Dual EMA (pos/neg split) along T. fp32 in/out.
//   pb = sigmoid(raw_pos_beta[e]); nb = sigmoid(raw_neg_beta[e])
//   mem_p[t] = pb*mem_p[t-1] + max(x,0)*(1-pb)
//   mem_n[t] = nb*mem_n[t-1] + min(x,0)*(1-nb)
//   out[t,b,e] = mem_p + mem_n
//
// Plan A: single cooperative kernel (x register-resident across phases,
//         finals/carries in d_ws, two grid.sync()).
// Plan B (if hipLaunchCooperativeKernel returns an error -- round 7 showed it
//         can fail silently): the round-6 3-kernel chunked scan (passed at
//         136.6 us). Host checks the return code; deterministic per call.

#define T_DIM 4096
#define B_DIM 8
#define E_DIM 512
#define CHUNK_L 16
#define NCHUNK (T_DIM / CHUNK_L)        // 256
#define BE (B_DIM * E_DIM)              // 4096 elements per t-step
#define FINALS (NCHUNK * B_DIM * E_DIM) // 1,048,576 floats per state

__device__ __forceinline__ float sigmoidf_(float x) { return 1.0f / (1.0f + __expf(-x)); }

// ---------------- Plan A: fused cooperative kernel ----------------
__global__ __launch_bounds__(256, 4) void ema_fused(
        const float* __restrict__ x,
        const float* __restrict__ rp,
        const float* __restrict__ rn,
        float* __restrict__ out,
        float* __restrict__ ws) {
    cg::grid_group grid = cg::this_grid();

    int gtid = blockIdx.x * 256 + threadIdx.x;
    int e4 = gtid & 127;          // E/4 = 128
    int b  = (gtid >> 7) & 7;
    int c  = gtid >> 10;          // 0..255
    int e  = e4 * 4;

    float4 rp4 = *(const float4*)(rp + e);
    float4 rn4 = *(const float4*)(rn + e);
    float bp[4] = {sigmoidf_(rp4.x), sigmoidf_(rp4.y), sigmoidf_(rp4.z), sigmoidf_(rp4.w)};
    float bn[4] = {sigmoidf_(rn4.x), sigmoidf_(rn4.y), sigmoidf_(rn4.z), sigmoidf_(rn4.w)};

    // phase 1: x tile -> registers; local scan with zero init
    float xr[64];
    float fp4[4] = {0.f, 0.f, 0.f, 0.f};
    float fn4[4] = {0.f, 0.f, 0.f, 0.f};
    int base = c * CHUNK_L * BE + b * E_DIM + e;
    #pragma unroll
    for (int k = 0; k < CHUNK_L; k++) {
        float4 xv = *(const float4*)(x + base + k * BE);
        xr[4*k+0] = xv.x; xr[4*k+1] = xv.y; xr[4*k+2] = xv.z; xr[4*k+3] = xv.w;
        #pragma unroll
        for (int j = 0; j < 4; j++) {
            float f = xr[4*k+j];
            fp4[j] = bp[j] * fp4[j] + fmaxf(f, 0.f) * (1.0f - bp[j]);
            fn4[j] = bn[j] * fn4[j] + fminf(f, 0.f) * (1.0f - bn[j]);
        }
    }
    int fi = (c * B_DIM + b) * E_DIM + e;
    *(float4*)(ws + fi)          = make_float4(fp4[0], fp4[1], fp4[2], fp4[3]);
    *(float4*)(ws + FINALS + fi) = make_float4(fn4[0], fn4[1], fn4[2], fn4[3]);

    grid.sync();

    // phase 2: carry scan across chunks (first 8192 threads)
    if (gtid < 2 * BE) {
        int ee = gtid & 511;
        int bb = (gtid >> 9) & 7;
        int s  = gtid >> 12;
        float beta = sigmoidf_(s ? rn[ee] : rp[ee]);
        float bl = beta * beta; bl = bl * bl; bl = bl * bl; bl = bl * bl;  // beta^16
        float* p = ws + s * FINALS + bb * E_DIM + ee;
        float carry = 0.f;
        for (int g = 0; g < NCHUNK / 16; g++) {
            float fv[16];
            #pragma unroll
            for (int u = 0; u < 16; u++) fv[u] = p[(g * 16 + u) * BE];
            #pragma unroll
            for (int u = 0; u < 16; u++) {
                p[(g * 16 + u) * BE] = carry;
                carry = bl * carry + fv[u];
            }
        }
    }

    grid.sync();

    // phase 3: re-scan from registers seeded with carries
    float4 cp = *(const float4*)(ws + fi);
    float4 cn = *(const float4*)(ws + FINALS + fi);
    float lp[4] = {cp.x, cp.y, cp.z, cp.w};
    float ln[4] = {cn.x, cn.y, cn.z, cn.w};
    #pragma unroll
    for (int k = 0; k < CHUNK_L; k++) {
        float o[4];
        #pragma unroll
        for (int j = 0; j < 4; j++) {
            float f = xr[4*k+j];
            lp[j] = bp[j] * lp[j] + fmaxf(f, 0.f) * (1.0f - bp[j]);
            ln[j] = bn[j] * ln[j] + fminf(f, 0.f) * (1.0f - bn[j]);
            o[j] = lp[j] + ln[j];
        }
        *(float4*)(out + base + k * BE) = make_float4(o[0], o[1], o[2], o[3]);
    }
}

// ---------------- Plan B: round-6 3-kernel pipeline (known good) ----------------
__global__ __launch_bounds__(256) void ParallelDLIEMA_17789754541002_kernel(
        const float* __restrict__ x,
        const float* __restrict__ rp,
        const float* __restrict__ rn,
        float* __restrict__ out) {
    int gtid = blockIdx.x * 256 + threadIdx.x;
    int e4 = gtid & 127;
    int b  = (gtid >> 7) & 7;
    int c  = gtid >> 10;
    int e  = e4 * 4;

    float4 rp4 = *(const float4*)(rp + e);
    float4 rn4 = *(const float4*)(rn + e);
    float bp[4] = {sigmoidf_(rp4.x), sigmoidf_(rp4.y), sigmoidf_(rp4.z), sigmoidf_(rp4.w)};
    float bn[4] = {sigmoidf_(rn4.x), sigmoidf_(rn4.y), sigmoidf_(rn4.z), sigmoidf_(rn4.w)};

    float fp4[4] = {0.f, 0.f, 0.f, 0.f};
    float fn4[4] = {0.f, 0.f, 0.f, 0.f};
    int base = c * CHUNK_L * BE + b * E_DIM + e;
    #pragma unroll
    for (int k = 0; k < CHUNK_L; k++) {
        float4 xv = *(const float4*)(x + base + k * BE);
        float f[4] = {xv.x, xv.y, xv.z, xv.w};
        #pragma unroll
        for (int j = 0; j < 4; j++) {
            fp4[j] = bp[j] * fp4[j] + fmaxf(f[j], 0.f) * (1.0f - bp[j]);
            fn4[j] = bn[j] * fn4[j] + fminf(f[j], 0.f) * (1.0f - bn[j]);
        }
    }
    *(float4*)(out + base + 0 * BE) = make_float4(fp4[0], fp4[1], fp4[2], fp4[3]);
    *(float4*)(out + base + 1 * BE) = make_float4(fn4[0], fn4[1], fn4[2], fn4[3]);
}

__global__ __launch_bounds__(256) void k_carry(const float* __restrict__ rp,
                                               const float* __restrict__ rn,
                                               float* __restrict__ out) {
    int gtid = blockIdx.x * 256 + threadIdx.x;
    int e = gtid & 511;
    int b = (gtid >> 9) & 7;
    int s = gtid >> 12;
    float beta = sigmoidf_(s ? rn[e] : rp[e]);
    float bl = beta * beta; bl = bl * bl; bl = bl * bl; bl = bl * bl;

    float* p = out + s * BE + b * E_DIM + e;
    float carry = 0.f;
    for (int g = 0; g < NCHUNK / 16; g++) {
        float fv[16];
        #pragma unroll
        for (int u = 0; u < 16; u++) fv[u] = p[(g * 16 + u) * (CHUNK_L * BE)];
        #pragma unroll
        for (int u = 0; u < 16; u++) {
            p[(g * 16 + u) * (CHUNK_L * BE)] = carry;
            carry = bl * carry + fv[u];
        }
    }
}

__global__ __launch_bounds__(256) void k_out(const float* __restrict__ x,
                                             const float* __restrict__ rp,
                                             const float* __restrict__ rn,
                                             float* __restrict__ out) {
    int gtid = blockIdx.x * 256 + threadIdx.x;
    int e4 = gtid & 127;
    int b  = (gtid >> 7) & 7;
    int c  = gtid >> 10;
    int e  = e4 * 4;

    float4 rp4 = *(const float4*)(rp + e);
    float4 rn4 = *(const float4*)(rn + e);
    float bp[4] = {sigmoidf_(rp4.x), sigmoidf_(rp4.y), sigmoidf_(rp4.z), sigmoidf_(rp4.w)};
    float bn[4] = {sigmoidf_(rn4.x), sigmoidf_(rn4.y), sigmoidf_(rn4.z), sigmoidf_(rn4.w)};

    int base = c * CHUNK_L * BE + b * E_DIM + e;
    float4 cp = *(const float4*)(out + base + 0 * BE);
    float4 cn = *(const float4*)(out + base + 1 * BE);
    float lp[4] = {cp.x, cp.y, cp.z, cp.w};
    float ln[4] = {cn.x, cn.y, cn.z, cn.w};

    #pragma unroll
    for (int k = 0; k < CHUNK_L; k++) {
        float4 xv = *(const float4*)(x + base + k * BE);
        float f[4] = {xv.x, xv.y, xv.z, xv.w};
        float o[4];
        #pragma unroll
        for (int j = 0; j < 4; j++) {
            lp[j] = bp[j] * lp[j] + fmaxf(f[j], 0.f) * (1.0f - bp[j]);
            ln[j] = bn[j] * ln[j] + fminf(f[j], 0.f) * (1.0f - bn[j]);
            o[j] = lp[j] + ln[j];
        }
        *(float4*)(out + base + k * BE) = make_float4(o[0], o[1], o[2], o[3]);
    }
}

extern "C" void kernel_launch(void* const* d_in, const int* in_sizes, int n_in,
                              void* d_out, int out_size, void* d_ws, size_t ws_size,
                              hipStream_t stream) {
    const float* x  = (const float*)d_in[0];
    const float* rp = (const float*)d_in[1];
    const float* rn = (const float*)d_in[2];
    float* out = (float*)d_out;
    float* ws  = (float*)d_ws;   // 16 MB used; d_ws is 256 MiB

    void* args[] = {(void*)&x, (void*)&rp, (void*)&rn, (void*)&out, (void*)&ws};
    hipError_t err = hipLaunchCooperativeKernel((void*)ema_fused, dim3(1024),
                                                dim3(256), args, 0, stream);
    if (err != hipSuccess) {
        // Plan B: known-good 3-kernel chunked scan (round 6, 136.6 us).
        ParallelDLIEMA_17789754541002_kernel<<<1024, 256, 0, stream>>>(x, rp, rn, out);
        k_carry<<<32, 256, 0, stream>>>(rp, rn, out);
        k_out<<<1024, 256, 0, stream>>>(x, rp, rn, out);
    }
}

// Round 9
// 361.559 us; speedup vs baseline: 1.1564x; 1.1564x over previous
//
#include <hip/hip_runtime.h>
#include <hip/hip_cooperative_groups.h>

namespace cg = cooperative_groups;

// T=4096, B=8, E=512. Dual EMA (pos/neg split) along T. fp32 in/out.
//   pb = sigmoid(raw_pos_beta[e]); nb = sigmoid(raw_neg_beta[e])
//   mem_p[t] = pb*mem_p[t-1] + max(x,0)*(1-pb)
//   mem_n[t] = nb*mem_n[t-1] + min(x,0)*(1-nb)
//   out[t,b,e] = mem_p + mem_n
//
// Round 9: fused cooperative kernel v2 — NO x register retention (round 8's
// xr[64] spilled to scratch: VGPR=64, WRITE inflated to 170 MB, 318 us +
// ~100 us overhead). Phase 3 re-reads x from global; x is L3-resident after
// phase 1 (64 MB << 256 MB L3), so the re-read is cheap and not HBM traffic.
// Fallback on launch error: round-6 3-kernel pipeline (known good, 136 us).

#define T_DIM 4096
#define B_DIM 8
#define E_DIM 512
#define CHUNK_L 16
#define NCHUNK (T_DIM / CHUNK_L)        // 256
#define BE (B_DIM * E_DIM)              // 4096 elements per t-step
#define FINALS (NCHUNK * B_DIM * E_DIM) // 1,048,576 floats per state

__device__ __forceinline__ float sigmoidf_(float x) { return 1.0f / (1.0f + __expf(-x)); }

// ---------------- Plan A v2: fused cooperative kernel, scratch-free ----------------
__global__ __launch_bounds__(256, 4) void ema_fused2(
        const float* __restrict__ x,
        const float* __restrict__ rp,
        const float* __restrict__ rn,
        float* __restrict__ out,
        float* __restrict__ ws) {
    cg::grid_group grid = cg::this_grid();

    int gtid = blockIdx.x * 256 + threadIdx.x;
    int e4 = gtid & 127;          // E/4 = 128
    int b  = (gtid >> 7) & 7;
    int c  = gtid >> 10;          // 0..255
    int e  = e4 * 4;

    float4 rp4 = *(const float4*)(rp + e);
    float4 rn4 = *(const float4*)(rn + e);
    float bp[4] = {sigmoidf_(rp4.x), sigmoidf_(rp4.y), sigmoidf_(rp4.z), sigmoidf_(rp4.w)};
    float bn[4] = {sigmoidf_(rn4.x), sigmoidf_(rn4.y), sigmoidf_(rn4.z), sigmoidf_(rn4.w)};

    // ---- phase 1: local scan (zero init), finals -> ws; x NOT retained ----
    float fp4[4] = {0.f, 0.f, 0.f, 0.f};
    float fn4[4] = {0.f, 0.f, 0.f, 0.f};
    int base = c * CHUNK_L * BE + b * E_DIM + e;
    #pragma unroll
    for (int k = 0; k < CHUNK_L; k++) {
        float4 xv = *(const float4*)(x + base + k * BE);
        float f[4] = {xv.x, xv.y, xv.z, xv.w};
        #pragma unroll
        for (int j = 0; j < 4; j++) {
            fp4[j] = bp[j] * fp4[j] + fmaxf(f[j], 0.f) * (1.0f - bp[j]);
            fn4[j] = bn[j] * fn4[j] + fminf(f[j], 0.f) * (1.0f - bn[j]);
        }
    }
    int fi = (c * B_DIM + b) * E_DIM + e;
    *(float4*)(ws + fi)          = make_float4(fp4[0], fp4[1], fp4[2], fp4[3]);
    *(float4*)(ws + FINALS + fi) = make_float4(fn4[0], fn4[1], fn4[2], fn4[3]);

    grid.sync();

    // ---- phase 2: carry scan across chunks (first 8192 threads) ----
    if (gtid < 2 * BE) {
        int ee = gtid & 511;
        int bb = (gtid >> 9) & 7;
        int s  = gtid >> 12;                   // 0 = pos, 1 = neg
        float beta = sigmoidf_(s ? rn[ee] : rp[ee]);
        float bl = beta * beta; bl = bl * bl; bl = bl * bl; bl = bl * bl;  // beta^16
        float* p = ws + s * FINALS + bb * E_DIM + ee;
        float carry = 0.f;
        for (int g = 0; g < NCHUNK / 16; g++) {
            float fv[16];
            #pragma unroll
            for (int u = 0; u < 16; u++) fv[u] = p[(g * 16 + u) * BE];
            #pragma unroll
            for (int u = 0; u < 16; u++) {
                p[(g * 16 + u) * BE] = carry;   // carry INTO chunk g*16+u
                carry = bl * carry + fv[u];
            }
        }
    }

    grid.sync();

    // ---- phase 3: re-read x (L3-hot), seed with carries, write out ----
    float4 cp = *(const float4*)(ws + fi);
    float4 cn = *(const float4*)(ws + FINALS + fi);
    float lp[4] = {cp.x, cp.y, cp.z, cp.w};
    float ln[4] = {cn.x, cn.y, cn.z, cn.w};
    #pragma unroll
    for (int k = 0; k < CHUNK_L; k++) {
        float4 xv = *(const float4*)(x + base + k * BE);
        float f[4] = {xv.x, xv.y, xv.z, xv.w};
        float o[4];
        #pragma unroll
        for (int j = 0; j < 4; j++) {
            lp[j] = bp[j] * lp[j] + fmaxf(f[j], 0.f) * (1.0f - bp[j]);
            ln[j] = bn[j] * ln[j] + fminf(f[j], 0.f) * (1.0f - bn[j]);
            o[j] = lp[j] + ln[j];
        }
        *(float4*)(out + base + k * BE) = make_float4(o[0], o[1], o[2], o[3]);
    }
}

// ---------------- Plan B: round-6 3-kernel pipeline (known good) ----------------
__global__ __launch_bounds__(256) void ParallelDLIEMA_17789754541002_kernel(
        const float* __restrict__ x,
        const float* __restrict__ rp,
        const float* __restrict__ rn,
        float* __restrict__ out) {
    int gtid = blockIdx.x * 256 + threadIdx.x;
    int e4 = gtid & 127;
    int b  = (gtid >> 7) & 7;
    int c  = gtid >> 10;
    int e  = e4 * 4;

    float4 rp4 = *(const float4*)(rp + e);
    float4 rn4 = *(const float4*)(rn + e);
    float bp[4] = {sigmoidf_(rp4.x), sigmoidf_(rp4.y), sigmoidf_(rp4.z), sigmoidf_(rp4.w)};
    float bn[4] = {sigmoidf_(rn4.x), sigmoidf_(rn4.y), sigmoidf_(rn4.z), sigmoidf_(rn4.w)};

    float fp4[4] = {0.f, 0.f, 0.f, 0.f};
    float fn4[4] = {0.f, 0.f, 0.f, 0.f};
    int base = c * CHUNK_L * BE + b * E_DIM + e;
    #pragma unroll
    for (int k = 0; k < CHUNK_L; k++) {
        float4 xv = *(const float4*)(x + base + k * BE);
        float f[4] = {xv.x, xv.y, xv.z, xv.w};
        #pragma unroll
        for (int j = 0; j < 4; j++) {
            fp4[j] = bp[j] * fp4[j] + fmaxf(f[j], 0.f) * (1.0f - bp[j]);
            fn4[j] = bn[j] * fn4[j] + fminf(f[j], 0.f) * (1.0f - bn[j]);
        }
    }
    *(float4*)(out + base + 0 * BE) = make_float4(fp4[0], fp4[1], fp4[2], fp4[3]);
    *(float4*)(out + base + 1 * BE) = make_float4(fn4[0], fn4[1], fn4[2], fn4[3]);
}

__global__ __launch_bounds__(256) void k_carry(const float* __restrict__ rp,
                                               const float* __restrict__ rn,
                                               float* __restrict__ out) {
    int gtid = blockIdx.x * 256 + threadIdx.x;
    int e = gtid & 511;
    int b = (gtid >> 9) & 7;
    int s = gtid >> 12;
    float beta = sigmoidf_(s ? rn[e] : rp[e]);
    float bl = beta * beta; bl = bl * bl; bl = bl * bl; bl = bl * bl;

    float* p = out + s * BE + b * E_DIM + e;
    float carry = 0.f;
    for (int g = 0; g < NCHUNK / 16; g++) {
        float fv[16];
        #pragma unroll
        for (int u = 0; u < 16; u++) fv[u] = p[(g * 16 + u) * (CHUNK_L * BE)];
        #pragma unroll
        for (int u = 0; u < 16; u++) {
            p[(g * 16 + u) * (CHUNK_L * BE)] = carry;
            carry = bl * carry + fv[u];
        }
    }
}

__global__ __launch_bounds__(256) void k_out(const float* __restrict__ x,
                                             const float* __restrict__ rp,
                                             const float* __restrict__ rn,
                                             float* __restrict__ out) {
    int gtid = blockIdx.x * 256 + threadIdx.x;
    int e4 = gtid & 127;
    int b  = (gtid >> 7) & 7;
    int c  = gtid >> 10;
    int e  = e4 * 4;

    float4 rp4 = *(const float4*)(rp + e);
    float4 rn4 = *(const float4*)(rn + e);
    float bp[4] = {sigmoidf_(rp4.x), sigmoidf_(rp4.y), sigmoidf_(rp4.z), sigmoidf_(rp4.w)};
    float bn[4] = {sigmoidf_(rn4.x), sigmoidf_(rn4.y), sigmoidf_(rn4.z), sigmoidf_(rn4.w)};

    int base = c * CHUNK_L * BE + b * E_DIM + e;
    float4 cp = *(const float4*)(out + base + 0 * BE);
    float4 cn = *(const float4*)(out + base + 1 * BE);
    float lp[4] = {cp.x, cp.y, cp.z, cp.w};
    float ln[4] = {cn.x, cn.y, cn.z, cn.w};

    #pragma unroll
    for (int k = 0; k < CHUNK_L; k++) {
        float4 xv = *(const float4*)(x + base + k * BE);
        float f[4] = {xv.x, xv.y, xv.z, xv.w};
        float o[4];
        #pragma unroll
        for (int j = 0; j < 4; j++) {
            lp[j] = bp[j] * lp[j] + fmaxf(f[j], 0.f) * (1.0f - bp[j]);
            ln[j] = bn[j] * ln[j] + fminf(f[j], 0.f) * (1.0f - bn[j]);
            o[j] = lp[j] + ln[j];
        }
        *(float4*)(out + base + k * BE) = make_float4(o[0], o[1], o[2], o[3]);
    }
}

extern "C" void kernel_launch(void* const* d_in, const int* in_sizes, int n_in,
                              void* d_out, int out_size, void* d_ws, size_t ws_size,
                              hipStream_t stream) {
    const float* x  = (const float*)d_in[0];
    const float* rp = (const float*)d_in[1];
    const float* rn = (const float*)d_in[2];
    float* out = (float*)d_out;
    float* ws  = (float*)d_ws;   // 8 MB used; d_ws is 256 MiB

    void* args[] = {(void*)&x, (void*)&rp, (void*)&rn, (void*)&out, (void*)&ws};
    hipError_t err = hipLaunchCooperativeKernel((void*)ema_fused2, dim3(1024),
                                                dim3(256), args, 0, stream);
    if (err != hipSuccess) {
        // Plan B: known-good 3-kernel chunked scan (round 6, 136.6 us).
        ParallelDLIEMA_17789754541002_kernel<<<1024, 256, 0, stream>>>(x, rp, rn, out);
        k_carry<<<32, 256, 0, stream>>>(rp, rn, out);
        k_out<<<1024, 256, 0, stream>>>(x, rp, rn, out);
    }
}